// Round 7
// baseline (697.295 us; speedup 1.0000x reference)
//
#include <hip/hip_runtime.h>

#define BATCH 32
#define NRr 32
#define NFf 128
#define NHh 64
#define NFHh 64
#define TI 4
#define GRID 512
#define SMEM_FLOATS 17696   // 70784 B -> 2 blocks/CU (141.6 of 160 KB), grid 512 co-resident

__device__ __forceinline__ float dot4(float4 a, float4 b) {
    return fmaf(a.x, b.x, fmaf(a.y, b.y, fmaf(a.z, b.z, a.w * b.w)));
}

// Device-scope grid barrier: per-phase counter (zeroed by hipMemsetAsync before
// launch). Safe because all GRID blocks are co-resident (see SMEM_FLOATS note).
__device__ __forceinline__ void grid_sync(unsigned* cnt) {
    __threadfence();              // release this thread's global writes (agent scope)
    __syncthreads();
    if (threadIdx.x == 0) {
        __hip_atomic_fetch_add(cnt, 1u, __ATOMIC_ACQ_REL, __HIP_MEMORY_SCOPE_AGENT);
        while (__hip_atomic_load(cnt, __ATOMIC_ACQUIRE, __HIP_MEMORY_SCOPE_AGENT) < (unsigned)GRID)
            __builtin_amdgcn_s_sleep(2);
        __threadfence();          // acquire: invalidate stale cache lines
    }
    __syncthreads();
}

// ---------------------------------------------------------------------------
// intra body: item decodes (tensor, b, chunk). Frontier uses 16-row chunks
// (8/batch) to fill the grid; others 32-row. sS rows padded to N+4 (bank fix).
// items: [0,32) robot, [32,288) frontier, [288,352) rh, [352,416) fh
// ---------------------------------------------------------------------------
__device__ void intra_body(int item, float* smem,
    const float* robot, const float* frontier, const float* rhist, const float* fhist,
    const float* Wq, const float* bq, const float* Wk, const float* bk,
    const float* Wv, const float* bv, const float* Wn1, const float* bn1,
    const float* Wn2, const float* bn2,
    float* o_robot, float* o_frontier, float* o_rh, float* o_fh)
{
    float* sXc = smem;          // 1024 (<=32 rows x 32)
    float* sQ  = smem + 1024;   // 1024
    float* sAgg= smem + 2048;   // 1024
    float* sS  = smem + 3072;   // 2304 (max CH*(N+4) = 32*68=2176 / 16*132=2112)
    float* sKT = smem + 5376;   // 4128  K^T [32][129]
    float* sVT = smem + 9504;   // 8192  V [N][32], then T [CH][256]

    const int tid = threadIdx.x;
    const float* xin; float* xout; int N, lgN, b, chunk, CH;
    if (item < 32)       { xin=robot;    xout=o_robot;    N=32;  lgN=5; b=item;  chunk=0;  CH=32; }
    else if (item < 288) { int t=item-32;  xin=frontier; xout=o_frontier; N=128; lgN=7; b=t>>3; chunk=t&7; CH=16; }
    else if (item < 352) { int t=item-288; xin=rhist;    xout=o_rh;       N=64;  lgN=6; b=t>>1; chunk=t&1; CH=32; }
    else                 { int t=item-352; xin=fhist;    xout=o_fh;       N=64;  lgN=6; b=t>>1; chunk=t&1; CH=32; }
    const int P = N + 4;
    const float* xb = xin + (size_t)b * N * 32;
    const int r0 = chunk * CH;
    const int d = tid & 31;

    __syncthreads();   // protect smem reuse across phase/loop boundaries

    // load CH rows of x into LDS
    for (int idx = tid; idx < (CH << 5); idx += 256)
        sXc[idx] = xb[(r0 << 5) + idx];

    // K^T, V for all N rows; weight rows hoisted
    {
        const float4* wk4 = (const float4*)(Wk + (d << 5));
        const float4* wv4 = (const float4*)(Wv + (d << 5));
        float4 wk[8], wv[8];
        #pragma unroll
        for (int k = 0; k < 8; ++k) { wk[k] = wk4[k]; wv[k] = wv4[k]; }
        const float bkd = bk[d], bvd = bv[d];
        for (int idx = tid; idx < (N << 5); idx += 256) {
            int j = idx >> 5;
            const float4* xr = (const float4*)(xb + (j << 5));
            float aK = bkd, aV = bvd;
            #pragma unroll
            for (int k = 0; k < 8; ++k) {
                float4 xv = xr[k];
                aK += dot4(wk[k], xv);
                aV += dot4(wv[k], xv);
            }
            sKT[d * 129 + j] = aK;
            sVT[(j << 5) + d] = aV;
        }
    }
    __syncthreads();

    // Q for CH rows
    {
        const float4* wq4 = (const float4*)(Wq + (d << 5));
        float4 wq[8];
        #pragma unroll
        for (int k = 0; k < 8; ++k) wq[k] = wq4[k];
        const float bqd = bq[d];
        for (int idx = tid; idx < (CH << 5); idx += 256) {
            int r = idx >> 5;
            const float4* xr = (const float4*)(sXc + (r << 5));
            float a = bqd;
            #pragma unroll
            for (int k = 0; k < 8; ++k) a += dot4(wq[k], xr[k]);
            sQ[idx] = a;
        }
    }
    __syncthreads();

    // scores: CH rows x N, row pitch P
    for (int idx = tid; idx < CH * N; idx += 256) {
        int r = idx >> lgN, j = idx & (N - 1);
        const float* qr = sQ + (r << 5);
        float a = 0.f;
        #pragma unroll
        for (int e = 0; e < 32; ++e) a = fmaf(qr[e], sKT[e * 129 + j], a);
        sS[r * P + j] = a;
    }
    __syncthreads();

    // softmax per row: lpr = 256/CH lanes per row (8 or 16), pitch P kills conflicts
    {
        const int lpr = 256 / CH;
        int r = tid / lpr, l = tid % lpr;
        float* row = sS + r * P;
        float m = -1e30f;
        for (int j = l; j < N; j += lpr) m = fmaxf(m, row[j]);
        for (int msk = lpr >> 1; msk; msk >>= 1) m = fmaxf(m, __shfl_xor(m, msk));
        float s = 0.f;
        for (int j = l; j < N; j += lpr) { float ev = __expf(row[j] - m); row[j] = ev; s += ev; }
        for (int msk = lpr >> 1; msk; msk >>= 1) s += __shfl_xor(s, msk);
        float inv = 1.0f / s;
        for (int j = l; j < N; j += lpr) row[j] *= inv;
    }
    __syncthreads();

    // agg = e @ V
    for (int idx = tid; idx < (CH << 5); idx += 256) {
        int r = idx >> 5;
        const float* er = sS + r * P;
        float a = 0.f;
        for (int j = 0; j < N; ++j) a = fmaf(er[j], sVT[(j << 5) + d], a);
        sAgg[idx] = a;
    }
    __syncthreads();

    // T = relu([x, agg] @ Wn1^T + bn1): thread h = tid, loop over CH rows
    float* sT = sVT;
    {
        const float4* w14 = (const float4*)(Wn1 + (tid << 6));
        float4 w1r[16];
        #pragma unroll
        for (int k = 0; k < 16; ++k) w1r[k] = w14[k];
        const float b1 = bn1[tid];
        for (int r = 0; r < CH; ++r) {
            const float4* xr = (const float4*)(sXc + (r << 5));
            const float4* ar = (const float4*)(sAgg + (r << 5));
            float a = b1;
            #pragma unroll
            for (int k = 0; k < 8; ++k) a += dot4(w1r[k], xr[k]);
            #pragma unroll
            for (int k = 0; k < 8; ++k) a += dot4(w1r[8 + k], ar[k]);
            sT[(r << 8) + tid] = fmaxf(a, 0.f);
        }
    }
    __syncthreads();

    // out = x + T @ Wn2^T + bn2: thread (rg, d), CH/8 rows each, h chunked
    {
        const int rg = tid >> 5;
        const int PR = CH >> 3;
        float acc[4] = {0.f, 0.f, 0.f, 0.f};
        #pragma unroll
        for (int hc = 0; hc < 4; ++hc) {
            const float4* w24 = (const float4*)(Wn2 + (d << 8) + (hc << 6));
            float4 w2r[16];
            #pragma unroll
            for (int k = 0; k < 16; ++k) w2r[k] = w24[k];
            for (int p = 0; p < PR; ++p) {
                int r = rg + (p << 3);
                const float4* tr = (const float4*)(sT + (r << 8) + (hc << 6));
                float a = 0.f;
                #pragma unroll
                for (int k = 0; k < 16; ++k) a += dot4(w2r[k], tr[k]);
                acc[p] += a;
            }
        }
        const float b2 = bn2[d];
        for (int p = 0; p < PR; ++p) {
            int r = rg + (p << 3);
            xout[((size_t)b * N << 5) + ((r0 + r) << 5) + d] = sXc[(r << 5) + d] + b2 + acc[p];
        }
    }
}

// ---------------------------------------------------------------------------
// pre_y body: item = 8 j's of the y-tensor. Emits yv (row-major) and w in
// transposed packed layout: wT flat = ((b*64 + h/4)*Ny + j)*4 + h%4
// ---------------------------------------------------------------------------
__device__ void pre_y_body(int item, float* smem,
    const float* yA, int NyA, float* wOutA, float* yvOutA, int nA,
    const float* yB, int NyB, float* wOutB, float* yvOutB,
    const float* Wk, const float* bk, const float* Wv, const float* bv,
    const float* We1)
{
    float* sY = smem;          // 256
    float* sK = smem + 256;    // 256
    const int tid = threadIdx.x;
    const float* y; int Ny; float* wOut; float* yvOut; int idx;
    if (item < nA) { y=yA; Ny=NyA; wOut=wOutA; yvOut=yvOutA; idx=item; }
    else           { y=yB; Ny=NyB; wOut=wOutB; yvOut=yvOutB; idx=item-nA; }
    const int chunks = Ny >> 3;
    const int b = idx / chunks, j0 = (idx - b * chunks) << 3;

    __syncthreads();
    sY[tid] = y[((size_t)(b * Ny + j0)) * 32 + tid];
    __syncthreads();

    {
        int jl = tid >> 5, dd = tid & 31;
        const float4* wk4 = (const float4*)(Wk + (dd << 5));
        const float4* wv4 = (const float4*)(Wv + (dd << 5));
        const float4* yr = (const float4*)(sY + (jl << 5));
        float aK = bk[dd], aV = bv[dd];
        #pragma unroll
        for (int k = 0; k < 8; ++k) {
            float4 yv4 = yr[k];
            aK += dot4(wk4[k], yv4);
            aV += dot4(wv4[k], yv4);
        }
        sK[(jl << 5) + dd] = aK;
        yvOut[((size_t)(b * Ny + j0 + jl)) * 32 + dd] = aV;
    }
    __syncthreads();

    {
        const float* w1 = We1 + tid * 65 + 32;
        float acc[8] = {0,0,0,0,0,0,0,0};
        #pragma unroll
        for (int e = 0; e < 32; ++e) {
            float we = w1[e];
            #pragma unroll
            for (int jl = 0; jl < 8; ++jl)
                acc[jl] = fmaf(we, sK[(jl << 5) + e], acc[jl]);
        }
        float* wbase = wOut + (((size_t)b * 64 + (tid >> 2)) * Ny + j0) * 4 + (tid & 3);
        #pragma unroll
        for (int jl = 0; jl < 8; ++jl)
            wbase[jl << 2] = acc[jl];
    }
}

// ---------------------------------------------------------------------------
// inter body (v5): item = (b, 4 i's). Phase 3 splits h across the 4 waves.
// ---------------------------------------------------------------------------
__device__ void inter_body(int item, float* smem,
    const float* xA, int NxA, const float* wA, const float* yvA,
    int NyA, const float* disA, float* outA, float* eA, int nBlkA,
    const float* xB, int NxB, const float* wB, const float* yvB,
    int NyB, const float* disB, float* outB, float* eB,
    const float* Wq, const float* bq,
    const float* We1, const float* be1, const float* We2,
    const float* Wn1, const float* bn1, const float* Wn2, const float* bn2)
{
    float* sX   = smem;          // 128
    float* sQ   = smem + 128;    // 128
    float* sAgg = smem + 256;    // 128
    float* sDis = smem + 384;    // 512  [4][128]
    float* sC   = smem + 896;    // 256
    float* sW2  = smem + 1152;   // 256
    float* sS   = smem + 1408;   // 512  [4][128]
    float* sUT  = smem + 1920;   // 1024 [4][256]: u (ph2-3), then T (ph7-8)
    float* sPR  = smem + 2944;   // 2048: score partials (ph3), then red (ph8)
    float* sYV  = smem + 4992;   // 4096: yv tile [Ny][32]

    const int tid = threadIdx.x;
    const float* x; int Nx; const float* w; const float* yv; int Ny;
    const float* dis; float* outp; float* ep; int idx;
    if (item < nBlkA) { x=xA; Nx=NxA; w=wA; yv=yvA; Ny=NyA; dis=disA; outp=outA; ep=eA; idx=item; }
    else              { x=xB; Nx=NxB; w=wB; yv=yvB; Ny=NyB; dis=disB; outp=outB; ep=eB; idx=item-nBlkA; }
    const int lgNy = (Ny == 128) ? 7 : 6;
    const int tiles = Nx >> 2;
    const int b = idx / tiles, i0 = (idx - b * tiles) << 2;
    const float* xrow = x + ((size_t)(b * Nx + i0)) * 32;

    __syncthreads();

    // phase 0: stage x, dis, yv
    if (tid < 128) sX[tid] = xrow[tid];
    if (tid < Ny) {
        int il = tid >> (lgNy - 2), jq = tid & ((Ny >> 2) - 1);
        ((float4*)sDis)[(il << 5) + jq] =
            ((const float4*)(dis + ((size_t)(b * Nx + i0 + il)) * Ny))[jq];
    }
    {
        const float4* yv4 = (const float4*)(yv + ((size_t)(b * Ny) << 5));
        for (int k = tid; k < (Ny << 3); k += 256)
            ((float4*)sYV)[k] = yv4[k];
    }
    __syncthreads();

    // phase 1: Q
    if (tid < 128) {
        int il = tid >> 5, dd = tid & 31;
        const float4* wq4 = (const float4*)(Wq + (dd << 5));
        const float4* xr = (const float4*)(sX + (il << 5));
        float a = bq[dd];
        #pragma unroll
        for (int k = 0; k < 8; ++k) a += dot4(wq4[k], xr[k]);
        sQ[tid] = a;
    }
    __syncthreads();

    // phase 2: u, c, w2
    {
        const float* w1 = We1 + tid * 65;
        const float b1 = be1[tid];
        float acc[TI];
        #pragma unroll
        for (int il = 0; il < TI; ++il) acc[il] = b1;
        #pragma unroll
        for (int e = 0; e < 32; ++e) {
            float we = w1[e];
            #pragma unroll
            for (int il = 0; il < TI; ++il)
                acc[il] = fmaf(we, sQ[(il << 5) + e], acc[il]);
        }
        #pragma unroll
        for (int il = 0; il < TI; ++il) sUT[(il << 8) + tid] = acc[il];
        sC[tid] = w1[64];
        sW2[tid] = We2[tid];
    }
    __syncthreads();

    // phase 3: scores; wave wv owns h-quarter, lane = j, all 4 i's
    const int wv = tid >> 6, lane = tid & 63;
    {
        const int hc0 = wv << 4;
        const float4* wT4 = (const float4*)w + (size_t)(b * 64) * Ny;
        const float4* c4p = (const float4*)sC;
        const float4* p4p = (const float4*)sW2;
        if (Ny == 64) {
            float dv[TI];
            #pragma unroll
            for (int il = 0; il < TI; ++il) dv[il] = sDis[(il << 7) + lane];
            float acc[TI] = {0.f, 0.f, 0.f, 0.f};
            #pragma unroll
            for (int t = 0; t < 16; ++t) {
                int hc = hc0 + t;
                float4 w4 = wT4[((size_t)hc << 6) + lane];
                float4 c4 = c4p[hc], p4 = p4p[hc];
                #pragma unroll
                for (int il = 0; il < TI; ++il) {
                    float4 u4 = ((const float4*)(sUT + (il << 8)))[hc];
                    acc[il] = fmaf(p4.x, fmaxf(fmaf(c4.x, dv[il], u4.x + w4.x), 0.f), acc[il]);
                    acc[il] = fmaf(p4.y, fmaxf(fmaf(c4.y, dv[il], u4.y + w4.y), 0.f), acc[il]);
                    acc[il] = fmaf(p4.z, fmaxf(fmaf(c4.z, dv[il], u4.z + w4.z), 0.f), acc[il]);
                    acc[il] = fmaf(p4.w, fmaxf(fmaf(c4.w, dv[il], u4.w + w4.w), 0.f), acc[il]);
                }
            }
            #pragma unroll
            for (int il = 0; il < TI; ++il)
                sPR[(wv << 9) + (il << 7) + lane] = acc[il];
        } else {
            float dv0[TI], dv1[TI];
            #pragma unroll
            for (int il = 0; il < TI; ++il) {
                dv0[il] = sDis[(il << 7) + lane];
                dv1[il] = sDis[(il << 7) + 64 + lane];
            }
            float acc0[TI] = {0.f, 0.f, 0.f, 0.f};
            float acc1[TI] = {0.f, 0.f, 0.f, 0.f};
            #pragma unroll
            for (int t = 0; t < 16; ++t) {
                int hc = hc0 + t;
                float4 wa = wT4[((size_t)hc << 7) + lane];
                float4 wb = wT4[((size_t)hc << 7) + 64 + lane];
                float4 c4 = c4p[hc], p4 = p4p[hc];
                #pragma unroll
                for (int il = 0; il < TI; ++il) {
                    float4 u4 = ((const float4*)(sUT + (il << 8)))[hc];
                    acc0[il] = fmaf(p4.x, fmaxf(fmaf(c4.x, dv0[il], u4.x + wa.x), 0.f), acc0[il]);
                    acc0[il] = fmaf(p4.y, fmaxf(fmaf(c4.y, dv0[il], u4.y + wa.y), 0.f), acc0[il]);
                    acc0[il] = fmaf(p4.z, fmaxf(fmaf(c4.z, dv0[il], u4.z + wa.z), 0.f), acc0[il]);
                    acc0[il] = fmaf(p4.w, fmaxf(fmaf(c4.w, dv0[il], u4.w + wa.w), 0.f), acc0[il]);
                    acc1[il] = fmaf(p4.x, fmaxf(fmaf(c4.x, dv1[il], u4.x + wb.x), 0.f), acc1[il]);
                    acc1[il] = fmaf(p4.y, fmaxf(fmaf(c4.y, dv1[il], u4.y + wb.y), 0.f), acc1[il]);
                    acc1[il] = fmaf(p4.z, fmaxf(fmaf(c4.z, dv1[il], u4.z + wb.z), 0.f), acc1[il]);
                    acc1[il] = fmaf(p4.w, fmaxf(fmaf(c4.w, dv1[il], u4.w + wb.w), 0.f), acc1[il]);
                }
            }
            #pragma unroll
            for (int il = 0; il < TI; ++il) {
                sPR[(wv << 9) + (il << 7) + lane] = acc0[il];
                sPR[(wv << 9) + (il << 7) + 64 + lane] = acc1[il];
            }
        }
    }
    __syncthreads();

    // reduce h-quarter partials
    for (int k = tid; k < (TI << lgNy); k += 256) {
        int il = k >> lgNy, j = k & (Ny - 1);
        int o = (il << 7) + j;
        sS[o] = sPR[o] + sPR[512 + o] + sPR[1024 + o] + sPR[1536 + o];
    }
    __syncthreads();

    // phase 4: softmax per wave + edge write
    {
        float v0 = sS[(wv << 7) + lane];
        float v1 = (Ny == 128) ? sS[(wv << 7) + 64 + lane] : -1e30f;
        float m = fmaxf(v0, v1);
        #pragma unroll
        for (int msk = 32; msk; msk >>= 1) m = fmaxf(m, __shfl_xor(m, msk));
        float e0 = __expf(v0 - m);
        float e1 = (Ny == 128) ? __expf(v1 - m) : 0.f;
        float s = e0 + e1;
        #pragma unroll
        for (int msk = 32; msk; msk >>= 1) s += __shfl_xor(s, msk);
        float inv = 1.0f / s;
        e0 *= inv; e1 *= inv;
        sS[(wv << 7) + lane] = e0;
        if (Ny == 128) sS[(wv << 7) + 64 + lane] = e1;
        if (ep) {
            float* erow = ep + ((size_t)(b * Nx + i0 + wv)) * Ny;
            erow[lane] = e0;
            if (Ny == 128) erow[64 + lane] = e1;
        }
    }

    // phase 5: agg = e @ yv (LDS)
    {
        const int dd = lane & 31, jg = lane >> 5;
        float p = 0.f;
        for (int j = jg; j < Ny; j += 2)
            p = fmaf(sS[(wv << 7) + j], sYV[(j << 5) + dd], p);
        p += __shfl_xor(p, 32);
        if (jg == 0) sAgg[(wv << 5) + dd] = p;
    }
    __syncthreads();

    // phase 7: node-MLP hidden (T overlays u)
    {
        const float4* w14 = (const float4*)(Wn1 + (tid << 6));
        const float b1 = bn1[tid];
        float acc[TI];
        #pragma unroll
        for (int il = 0; il < TI; ++il) acc[il] = b1;
        #pragma unroll
        for (int k = 0; k < 8; ++k) {
            float4 wa = w14[k];
            #pragma unroll
            for (int il = 0; il < TI; ++il)
                acc[il] += dot4(wa, ((const float4*)(sX + (il << 5)))[k]);
        }
        #pragma unroll
        for (int k = 0; k < 8; ++k) {
            float4 wb = w14[8 + k];
            #pragma unroll
            for (int il = 0; il < TI; ++il)
                acc[il] += dot4(wb, ((const float4*)(sAgg + (il << 5)))[k]);
        }
        __syncthreads();
        #pragma unroll
        for (int il = 0; il < TI; ++il) sUT[(il << 8) + tid] = fmaxf(acc[il], 0.f);
    }
    __syncthreads();

    // phase 8: out = x + T @ Wn2^T + bn2
    {
        const int hg = tid >> 5, dd = tid & 31;
        const float4* w24 = (const float4*)(Wn2 + (dd << 8) + (hg << 5));
        float4 w2r[8];
        #pragma unroll
        for (int k = 0; k < 8; ++k) w2r[k] = w24[k];
        float p[TI] = {0.f, 0.f, 0.f, 0.f};
        #pragma unroll
        for (int k = 0; k < 8; ++k) {
            #pragma unroll
            for (int il = 0; il < TI; ++il)
                p[il] += dot4(w2r[k], ((const float4*)(sUT + (il << 8) + (hg << 5)))[k]);
        }
        #pragma unroll
        for (int il = 0; il < TI; ++il) sPR[(hg << 7) + (il << 5) + dd] = p[il];
    }
    __syncthreads();
    if (tid < 128) {
        int il = tid >> 5, dd = tid & 31;
        float a = bn2[dd] + sX[tid];
        #pragma unroll
        for (int hg = 0; hg < 8; ++hg) a += sPR[(hg << 7) + tid];
        outp[((size_t)(b * Nx + i0 + il)) * 32 + dd] = a;
    }
}

// ---------------------------------------------------------------------------
// mega kernel: all 5 stages, 4 grid barriers, one launch.
// GRID=512 co-residency proof: LDS 70784B -> 2 blocks/CU (141.6 <= 160 KB);
// VGPR <= 256 -> 8 waves/CU; 2 x 256 CUs = 512. All blocks resident => barrier safe.
// ---------------------------------------------------------------------------
__global__ __launch_bounds__(256) void mega_kernel(
    const float* robot, const float* frontier, const float* rh, const float* fh,
    const float* robot_frontier, const float* robot_past, const float* frontier_past,
    const float* Wq, const float* bq, const float* Wk, const float* bk,
    const float* Wv, const float* bv, const float* Wn1, const float* bn1,
    const float* Wn2, const float* bn2, const float* We1, const float* be1,
    const float* We2,
    float* out_robot, float* out_frontier, float* out_rh, float* out_fh, float* out_edge,
    float* robot1, float* robot2, float* nf,
    float* w5, float* yv5, float* w6, float* yv6, float* w7, float* yv7,
    unsigned* bar)
{
    __shared__ __align__(16) float smem[SMEM_FLOATS];

    // stage 1: four intra-attentions (416 items)
    for (int it = blockIdx.x; it < 416; it += GRID)
        intra_body(it, smem, robot, frontier, rh, fh,
                   Wq, bq, Wk, bk, Wv, bv, Wn1, bn1, Wn2, bn2,
                   robot1, out_frontier, out_rh, out_fh);
    grid_sync(bar + 0);

    // stage 2: pre_y for inter5 (y=rh1) and inter6 (y=fh1) — 512 items
    for (int it = blockIdx.x; it < 512; it += GRID)
        pre_y_body(it, smem, out_rh, NHh, w5, yv5, BATCH * NHh / 8,
                   out_fh, NFHh, w6, yv6, Wk, bk, Wv, bv, We1);
    grid_sync(bar + 1);

    // stage 3: inter5 (robot1 x rh1) + inter6 (frontier1 x fh1) — 1280 items
    for (int it = blockIdx.x; it < 1280; it += GRID)
        inter_body(it, smem,
                   robot1, NRr, w5, yv5, NHh, robot_past, robot2, (float*)0, BATCH * (NRr / TI),
                   out_frontier, NFf, w6, yv6, NFHh, frontier_past, nf, (float*)0,
                   Wq, bq, We1, be1, We2, Wn1, bn1, Wn2, bn2);
    grid_sync(bar + 2);

    // stage 4: pre_y for inter7 (y = new_frontier) — 512 items
    for (int it = blockIdx.x; it < 512; it += GRID)
        pre_y_body(it, smem, nf, NFf, w7, yv7, BATCH * NFf / 8,
                   nf, NFf, w7, yv7, Wk, bk, Wv, bv, We1);
    grid_sync(bar + 3);

    // stage 5: inter7 (robot2 x new_frontier) -> final robot + edge — 256 items
    for (int it = blockIdx.x; it < 256; it += GRID)
        inter_body(it, smem,
                   robot2, NRr, w7, yv7, NFf, robot_frontier, out_robot, out_edge, BATCH * (NRr / TI),
                   robot2, NRr, w7, yv7, NFf, robot_frontier, out_robot, out_edge,
                   Wq, bq, We1, be1, We2, Wn1, bn1, Wn2, bn2);
}

// ---------------------------------------------------------------------------
extern "C" void kernel_launch(void* const* d_in, const int* in_sizes, int n_in,
                              void* d_out, int out_size, void* d_ws, size_t ws_size,
                              hipStream_t stream) {
    const float* robot          = (const float*)d_in[0];
    const float* frontier       = (const float*)d_in[1];
    const float* rh             = (const float*)d_in[2];
    const float* fh             = (const float*)d_in[3];
    const float* robot_frontier = (const float*)d_in[4];
    const float* robot_past     = (const float*)d_in[5];
    const float* frontier_past  = (const float*)d_in[6];
    const float* Wq  = (const float*)d_in[7];  const float* bq  = (const float*)d_in[8];
    const float* Wk  = (const float*)d_in[9];  const float* bk  = (const float*)d_in[10];
    const float* Wv  = (const float*)d_in[11]; const float* bv  = (const float*)d_in[12];
    const float* Wn1 = (const float*)d_in[13]; const float* bn1 = (const float*)d_in[14];
    const float* Wn2 = (const float*)d_in[15]; const float* bn2 = (const float*)d_in[16];
    const float* We1 = (const float*)d_in[17]; const float* be1 = (const float*)d_in[18];
    const float* We2 = (const float*)d_in[19];

    float* out = (float*)d_out;
    float* out_robot    = out;            // 32*32*32   = 32768
    float* out_frontier = out + 32768;    // 32*128*32  = 131072
    float* out_rh       = out + 163840;   // 32*64*32   = 65536
    float* out_fh       = out + 229376;   // 32*64*32   = 65536
    float* out_edge     = out + 294912;   // 32*32*128  = 131072

    float* W = (float*)d_ws;
    float* robot1 = W;                 // 32768
    float* robot2 = W + 32768;         // 32768
    float* nf     = W + 65536;         // 131072
    float* w5     = W + 196608;        // 32*64*256  = 524288 (wT layout)
    float* yv5    = W + 720896;        // 65536
    float* w6     = W + 786432;        // 524288 (wT layout)
    float* yv6    = W + 1310720;       // 65536
    float* w7     = W + 1376256;       // 32*128*256 = 1048576 (wT layout)
    float* yv7    = W + 2424832;       // 131072 -> ends 2555904
    unsigned* bar = (unsigned*)(W + 2555904);  // 4 barrier counters

    hipMemsetAsync(bar, 0, 64, stream);
    mega_kernel<<<GRID, 256, 0, stream>>>(
        robot, frontier, rh, fh, robot_frontier, robot_past, frontier_past,
        Wq, bq, Wk, bk, Wv, bv, Wn1, bn1, Wn2, bn2, We1, be1, We2,
        out_robot, out_frontier, out_rh, out_fh, out_edge,
        robot1, robot2, nf, w5, yv5, w6, yv6, w7, yv7, bar);
}

// Round 8
// 394.478 us; speedup vs baseline: 1.7676x; 1.7676x over previous
//
#include <hip/hip_runtime.h>

#define BATCH 32
#define NRr 32
#define NFf 128
#define NHh 64
#define NFHh 64
#define TI 4
#define GRID 512
#define SMEM_FLOATS 17696   // 70784 B -> 2 blocks/CU (141.6 of 160 KB), grid 512 co-resident

__device__ __forceinline__ float dot4(float4 a, float4 b) {
    return fmaf(a.x, b.x, fmaf(a.y, b.y, fmaf(a.z, b.z, a.w * b.w)));
}

// Grid barrier, cache-friendly: one ACQ_REL RMW (release: wbl2 once), RELAXED
// polls (no buffer_inv per iteration — the R7 bug), one final ACQUIRE load
// (single buffer_inv). All GRID blocks are co-resident by construction.
__device__ __forceinline__ void grid_sync(unsigned* cnt) {
    __syncthreads();   // all waves' prior vmem ops drained (vmcnt0) before signal
    if (threadIdx.x == 0) {
        __hip_atomic_fetch_add(cnt, 1u, __ATOMIC_ACQ_REL, __HIP_MEMORY_SCOPE_AGENT);
        while (__hip_atomic_load(cnt, __ATOMIC_RELAXED, __HIP_MEMORY_SCOPE_AGENT) < (unsigned)GRID)
            __builtin_amdgcn_s_sleep(8);
        (void)__hip_atomic_load(cnt, __ATOMIC_ACQUIRE, __HIP_MEMORY_SCOPE_AGENT);  // one inv
    }
    __syncthreads();
}

// ---------------------------------------------------------------------------
// intra body: item decodes (tensor, b, chunk). Frontier uses 16-row chunks
// (8/batch) to fill the grid; others 32-row. sS rows padded to N+4 (bank fix).
// items: [0,32) robot, [32,288) frontier, [288,352) rh, [352,416) fh
// ---------------------------------------------------------------------------
__device__ void intra_body(int item, float* smem,
    const float* robot, const float* frontier, const float* rhist, const float* fhist,
    const float* Wq, const float* bq, const float* Wk, const float* bk,
    const float* Wv, const float* bv, const float* Wn1, const float* bn1,
    const float* Wn2, const float* bn2,
    float* o_robot, float* o_frontier, float* o_rh, float* o_fh)
{
    float* sXc = smem;          // 1024 (<=32 rows x 32)
    float* sQ  = smem + 1024;   // 1024
    float* sAgg= smem + 2048;   // 1024
    float* sS  = smem + 3072;   // 2304 (max CH*(N+4))
    float* sKT = smem + 5376;   // 4128  K^T [32][129]
    float* sVT = smem + 9504;   // 8192  V [N][32], then T [CH][256]

    const int tid = threadIdx.x;
    const float* xin; float* xout; int N, lgN, b, chunk, CH;
    if (item < 32)       { xin=robot;    xout=o_robot;    N=32;  lgN=5; b=item;  chunk=0;  CH=32; }
    else if (item < 288) { int t=item-32;  xin=frontier; xout=o_frontier; N=128; lgN=7; b=t>>3; chunk=t&7; CH=16; }
    else if (item < 352) { int t=item-288; xin=rhist;    xout=o_rh;       N=64;  lgN=6; b=t>>1; chunk=t&1; CH=32; }
    else                 { int t=item-352; xin=fhist;    xout=o_fh;       N=64;  lgN=6; b=t>>1; chunk=t&1; CH=32; }
    const int P = N + 4;
    const float* xb = xin + (size_t)b * N * 32;
    const int r0 = chunk * CH;
    const int d = tid & 31;

    __syncthreads();   // protect smem reuse across item/stage boundaries

    // load CH rows of x into LDS
    for (int idx = tid; idx < (CH << 5); idx += 256)
        sXc[idx] = xb[(r0 << 5) + idx];

    // K^T, V for all N rows; weight rows hoisted
    {
        const float4* wk4 = (const float4*)(Wk + (d << 5));
        const float4* wv4 = (const float4*)(Wv + (d << 5));
        float4 wk[8], wv[8];
        #pragma unroll
        for (int k = 0; k < 8; ++k) { wk[k] = wk4[k]; wv[k] = wv4[k]; }
        const float bkd = bk[d], bvd = bv[d];
        for (int idx = tid; idx < (N << 5); idx += 256) {
            int j = idx >> 5;
            const float4* xr = (const float4*)(xb + (j << 5));
            float aK = bkd, aV = bvd;
            #pragma unroll
            for (int k = 0; k < 8; ++k) {
                float4 xv = xr[k];
                aK += dot4(wk[k], xv);
                aV += dot4(wv[k], xv);
            }
            sKT[d * 129 + j] = aK;
            sVT[(j << 5) + d] = aV;
        }
    }
    __syncthreads();

    // Q for CH rows
    {
        const float4* wq4 = (const float4*)(Wq + (d << 5));
        float4 wq[8];
        #pragma unroll
        for (int k = 0; k < 8; ++k) wq[k] = wq4[k];
        const float bqd = bq[d];
        for (int idx = tid; idx < (CH << 5); idx += 256) {
            int r = idx >> 5;
            const float4* xr = (const float4*)(sXc + (r << 5));
            float a = bqd;
            #pragma unroll
            for (int k = 0; k < 8; ++k) a += dot4(wq[k], xr[k]);
            sQ[idx] = a;
        }
    }
    __syncthreads();

    // scores: CH rows x N, row pitch P
    for (int idx = tid; idx < CH * N; idx += 256) {
        int r = idx >> lgN, j = idx & (N - 1);
        const float* qr = sQ + (r << 5);
        float a = 0.f;
        #pragma unroll
        for (int e = 0; e < 32; ++e) a = fmaf(qr[e], sKT[e * 129 + j], a);
        sS[r * P + j] = a;
    }
    __syncthreads();

    // softmax per row: lpr = 256/CH lanes per row, pitch P kills conflicts
    {
        const int lpr = 256 / CH;
        int r = tid / lpr, l = tid % lpr;
        float* row = sS + r * P;
        float m = -1e30f;
        for (int j = l; j < N; j += lpr) m = fmaxf(m, row[j]);
        for (int msk = lpr >> 1; msk; msk >>= 1) m = fmaxf(m, __shfl_xor(m, msk));
        float s = 0.f;
        for (int j = l; j < N; j += lpr) { float ev = __expf(row[j] - m); row[j] = ev; s += ev; }
        for (int msk = lpr >> 1; msk; msk >>= 1) s += __shfl_xor(s, msk);
        float inv = 1.0f / s;
        for (int j = l; j < N; j += lpr) row[j] *= inv;
    }
    __syncthreads();

    // agg = e @ V
    for (int idx = tid; idx < (CH << 5); idx += 256) {
        int r = idx >> 5;
        const float* er = sS + r * P;
        float a = 0.f;
        for (int j = 0; j < N; ++j) a = fmaf(er[j], sVT[(j << 5) + d], a);
        sAgg[idx] = a;
    }
    __syncthreads();

    // T = relu([x, agg] @ Wn1^T + bn1): thread h = tid, loop over CH rows
    float* sT = sVT;
    {
        const float4* w14 = (const float4*)(Wn1 + (tid << 6));
        float4 w1r[16];
        #pragma unroll
        for (int k = 0; k < 16; ++k) w1r[k] = w14[k];
        const float b1 = bn1[tid];
        for (int r = 0; r < CH; ++r) {
            const float4* xr = (const float4*)(sXc + (r << 5));
            const float4* ar = (const float4*)(sAgg + (r << 5));
            float a = b1;
            #pragma unroll
            for (int k = 0; k < 8; ++k) a += dot4(w1r[k], xr[k]);
            #pragma unroll
            for (int k = 0; k < 8; ++k) a += dot4(w1r[8 + k], ar[k]);
            sT[(r << 8) + tid] = fmaxf(a, 0.f);
        }
    }
    __syncthreads();

    // out = x + T @ Wn2^T + bn2: thread (rg, d), CH/8 rows each, h chunked
    {
        const int rg = tid >> 5;
        const int PR = CH >> 3;
        float acc[4] = {0.f, 0.f, 0.f, 0.f};
        #pragma unroll
        for (int hc = 0; hc < 4; ++hc) {
            const float4* w24 = (const float4*)(Wn2 + (d << 8) + (hc << 6));
            float4 w2r[16];
            #pragma unroll
            for (int k = 0; k < 16; ++k) w2r[k] = w24[k];
            for (int p = 0; p < PR; ++p) {
                int r = rg + (p << 3);
                const float4* tr = (const float4*)(sT + (r << 8) + (hc << 6));
                float a = 0.f;
                #pragma unroll
                for (int k = 0; k < 16; ++k) a += dot4(w2r[k], tr[k]);
                acc[p] += a;
            }
        }
        const float b2 = bn2[d];
        for (int p = 0; p < PR; ++p) {
            int r = rg + (p << 3);
            xout[((size_t)b * N << 5) + ((r0 + r) << 5) + d] = sXc[(r << 5) + d] + b2 + acc[p];
        }
    }
}

// ---------------------------------------------------------------------------
// pre_y body: item = 8 j's of the y-tensor. Emits yv (row-major) and w in
// transposed packed layout: wT flat = ((b*64 + h/4)*Ny + j)*4 + h%4
// ---------------------------------------------------------------------------
__device__ void pre_y_body(int item, float* smem,
    const float* yA, int NyA, float* wOutA, float* yvOutA, int nA,
    const float* yB, int NyB, float* wOutB, float* yvOutB,
    const float* Wk, const float* bk, const float* Wv, const float* bv,
    const float* We1)
{
    float* sY = smem;          // 256
    float* sK = smem + 256;    // 256
    const int tid = threadIdx.x;
    const float* y; int Ny; float* wOut; float* yvOut; int idx;
    if (item < nA) { y=yA; Ny=NyA; wOut=wOutA; yvOut=yvOutA; idx=item; }
    else           { y=yB; Ny=NyB; wOut=wOutB; yvOut=yvOutB; idx=item-nA; }
    const int chunks = Ny >> 3;
    const int b = idx / chunks, j0 = (idx - b * chunks) << 3;

    __syncthreads();
    sY[tid] = y[((size_t)(b * Ny + j0)) * 32 + tid];
    __syncthreads();

    {
        int jl = tid >> 5, dd = tid & 31;
        const float4* wk4 = (const float4*)(Wk + (dd << 5));
        const float4* wv4 = (const float4*)(Wv + (dd << 5));
        const float4* yr = (const float4*)(sY + (jl << 5));
        float aK = bk[dd], aV = bv[dd];
        #pragma unroll
        for (int k = 0; k < 8; ++k) {
            float4 yv4 = yr[k];
            aK += dot4(wk4[k], yv4);
            aV += dot4(wv4[k], yv4);
        }
        sK[(jl << 5) + dd] = aK;
        yvOut[((size_t)(b * Ny + j0 + jl)) * 32 + dd] = aV;
    }
    __syncthreads();

    {
        const float* w1 = We1 + tid * 65 + 32;
        float acc[8] = {0,0,0,0,0,0,0,0};
        #pragma unroll
        for (int e = 0; e < 32; ++e) {
            float we = w1[e];
            #pragma unroll
            for (int jl = 0; jl < 8; ++jl)
                acc[jl] = fmaf(we, sK[(jl << 5) + e], acc[jl]);
        }
        float* wbase = wOut + (((size_t)b * 64 + (tid >> 2)) * Ny + j0) * 4 + (tid & 3);
        #pragma unroll
        for (int jl = 0; jl < 8; ++jl)
            wbase[jl << 2] = acc[jl];
    }
}

// ---------------------------------------------------------------------------
// inter body (v5): item = (b, 4 i's). Phase 3 splits h across the 4 waves.
// ---------------------------------------------------------------------------
__device__ void inter_body(int item, float* smem,
    const float* xA, int NxA, const float* wA, const float* yvA,
    int NyA, const float* disA, float* outA, float* eA, int nBlkA,
    const float* xB, int NxB, const float* wB, const float* yvB,
    int NyB, const float* disB, float* outB, float* eB,
    const float* Wq, const float* bq,
    const float* We1, const float* be1, const float* We2,
    const float* Wn1, const float* bn1, const float* Wn2, const float* bn2)
{
    float* sX   = smem;          // 128
    float* sQ   = smem + 128;    // 128
    float* sAgg = smem + 256;    // 128
    float* sDis = smem + 384;    // 512  [4][128]
    float* sC   = smem + 896;    // 256
    float* sW2  = smem + 1152;   // 256
    float* sS   = smem + 1408;   // 512  [4][128]
    float* sUT  = smem + 1920;   // 1024 [4][256]: u (ph2-3), then T (ph7-8)
    float* sPR  = smem + 2944;   // 2048: score partials (ph3), then red (ph8)
    float* sYV  = smem + 4992;   // 4096: yv tile [Ny][32]

    const int tid = threadIdx.x;
    const float* x; int Nx; const float* w; const float* yv; int Ny;
    const float* dis; float* outp; float* ep; int idx;
    if (item < nBlkA) { x=xA; Nx=NxA; w=wA; yv=yvA; Ny=NyA; dis=disA; outp=outA; ep=eA; idx=item; }
    else              { x=xB; Nx=NxB; w=wB; yv=yvB; Ny=NyB; dis=disB; outp=outB; ep=eB; idx=item-nBlkA; }
    const int lgNy = (Ny == 128) ? 7 : 6;
    const int tiles = Nx >> 2;
    const int b = idx / tiles, i0 = (idx - b * tiles) << 2;
    const float* xrow = x + ((size_t)(b * Nx + i0)) * 32;

    __syncthreads();

    // phase 0: stage x, dis, yv
    if (tid < 128) sX[tid] = xrow[tid];
    if (tid < Ny) {
        int il = tid >> (lgNy - 2), jq = tid & ((Ny >> 2) - 1);
        ((float4*)sDis)[(il << 5) + jq] =
            ((const float4*)(dis + ((size_t)(b * Nx + i0 + il)) * Ny))[jq];
    }
    {
        const float4* yv4 = (const float4*)(yv + ((size_t)(b * Ny) << 5));
        for (int k = tid; k < (Ny << 3); k += 256)
            ((float4*)sYV)[k] = yv4[k];
    }
    __syncthreads();

    // phase 1: Q
    if (tid < 128) {
        int il = tid >> 5, dd = tid & 31;
        const float4* wq4 = (const float4*)(Wq + (dd << 5));
        const float4* xr = (const float4*)(sX + (il << 5));
        float a = bq[dd];
        #pragma unroll
        for (int k = 0; k < 8; ++k) a += dot4(wq4[k], xr[k]);
        sQ[tid] = a;
    }
    __syncthreads();

    // phase 2: u, c, w2
    {
        const float* w1 = We1 + tid * 65;
        const float b1 = be1[tid];
        float acc[TI];
        #pragma unroll
        for (int il = 0; il < TI; ++il) acc[il] = b1;
        #pragma unroll
        for (int e = 0; e < 32; ++e) {
            float we = w1[e];
            #pragma unroll
            for (int il = 0; il < TI; ++il)
                acc[il] = fmaf(we, sQ[(il << 5) + e], acc[il]);
        }
        #pragma unroll
        for (int il = 0; il < TI; ++il) sUT[(il << 8) + tid] = acc[il];
        sC[tid] = w1[64];
        sW2[tid] = We2[tid];
    }
    __syncthreads();

    // phase 3: scores; wave wv owns h-quarter, lane = j, all 4 i's
    const int wv = tid >> 6, lane = tid & 63;
    {
        const int hc0 = wv << 4;
        const float4* wT4 = (const float4*)w + (size_t)(b * 64) * Ny;
        const float4* c4p = (const float4*)sC;
        const float4* p4p = (const float4*)sW2;
        if (Ny == 64) {
            float dv[TI];
            #pragma unroll
            for (int il = 0; il < TI; ++il) dv[il] = sDis[(il << 7) + lane];
            float acc[TI] = {0.f, 0.f, 0.f, 0.f};
            #pragma unroll
            for (int t = 0; t < 16; ++t) {
                int hc = hc0 + t;
                float4 w4 = wT4[((size_t)hc << 6) + lane];
                float4 c4 = c4p[hc], p4 = p4p[hc];
                #pragma unroll
                for (int il = 0; il < TI; ++il) {
                    float4 u4 = ((const float4*)(sUT + (il << 8)))[hc];
                    acc[il] = fmaf(p4.x, fmaxf(fmaf(c4.x, dv[il], u4.x + w4.x), 0.f), acc[il]);
                    acc[il] = fmaf(p4.y, fmaxf(fmaf(c4.y, dv[il], u4.y + w4.y), 0.f), acc[il]);
                    acc[il] = fmaf(p4.z, fmaxf(fmaf(c4.z, dv[il], u4.z + w4.z), 0.f), acc[il]);
                    acc[il] = fmaf(p4.w, fmaxf(fmaf(c4.w, dv[il], u4.w + w4.w), 0.f), acc[il]);
                }
            }
            #pragma unroll
            for (int il = 0; il < TI; ++il)
                sPR[(wv << 9) + (il << 7) + lane] = acc[il];
        } else {
            float dv0[TI], dv1[TI];
            #pragma unroll
            for (int il = 0; il < TI; ++il) {
                dv0[il] = sDis[(il << 7) + lane];
                dv1[il] = sDis[(il << 7) + 64 + lane];
            }
            float acc0[TI] = {0.f, 0.f, 0.f, 0.f};
            float acc1[TI] = {0.f, 0.f, 0.f, 0.f};
            #pragma unroll
            for (int t = 0; t < 16; ++t) {
                int hc = hc0 + t;
                float4 wa = wT4[((size_t)hc << 7) + lane];
                float4 wb = wT4[((size_t)hc << 7) + 64 + lane];
                float4 c4 = c4p[hc], p4 = p4p[hc];
                #pragma unroll
                for (int il = 0; il < TI; ++il) {
                    float4 u4 = ((const float4*)(sUT + (il << 8)))[hc];
                    acc0[il] = fmaf(p4.x, fmaxf(fmaf(c4.x, dv0[il], u4.x + wa.x), 0.f), acc0[il]);
                    acc0[il] = fmaf(p4.y, fmaxf(fmaf(c4.y, dv0[il], u4.y + wa.y), 0.f), acc0[il]);
                    acc0[il] = fmaf(p4.z, fmaxf(fmaf(c4.z, dv0[il], u4.z + wa.z), 0.f), acc0[il]);
                    acc0[il] = fmaf(p4.w, fmaxf(fmaf(c4.w, dv0[il], u4.w + wa.w), 0.f), acc0[il]);
                    acc1[il] = fmaf(p4.x, fmaxf(fmaf(c4.x, dv1[il], u4.x + wb.x), 0.f), acc1[il]);
                    acc1[il] = fmaf(p4.y, fmaxf(fmaf(c4.y, dv1[il], u4.y + wb.y), 0.f), acc1[il]);
                    acc1[il] = fmaf(p4.z, fmaxf(fmaf(c4.z, dv1[il], u4.z + wb.z), 0.f), acc1[il]);
                    acc1[il] = fmaf(p4.w, fmaxf(fmaf(c4.w, dv1[il], u4.w + wb.w), 0.f), acc1[il]);
                }
            }
            #pragma unroll
            for (int il = 0; il < TI; ++il) {
                sPR[(wv << 9) + (il << 7) + lane] = acc0[il];
                sPR[(wv << 9) + (il << 7) + 64 + lane] = acc1[il];
            }
        }
    }
    __syncthreads();

    // reduce h-quarter partials
    for (int k = tid; k < (TI << lgNy); k += 256) {
        int il = k >> lgNy, j = k & (Ny - 1);
        int o = (il << 7) + j;
        sS[o] = sPR[o] + sPR[512 + o] + sPR[1024 + o] + sPR[1536 + o];
    }
    __syncthreads();

    // phase 4: softmax per wave + edge write
    {
        float v0 = sS[(wv << 7) + lane];
        float v1 = (Ny == 128) ? sS[(wv << 7) + 64 + lane] : -1e30f;
        float m = fmaxf(v0, v1);
        #pragma unroll
        for (int msk = 32; msk; msk >>= 1) m = fmaxf(m, __shfl_xor(m, msk));
        float e0 = __expf(v0 - m);
        float e1 = (Ny == 128) ? __expf(v1 - m) : 0.f;
        float s = e0 + e1;
        #pragma unroll
        for (int msk = 32; msk; msk >>= 1) s += __shfl_xor(s, msk);
        float inv = 1.0f / s;
        e0 *= inv; e1 *= inv;
        sS[(wv << 7) + lane] = e0;
        if (Ny == 128) sS[(wv << 7) + 64 + lane] = e1;
        if (ep) {
            float* erow = ep + ((size_t)(b * Nx + i0 + wv)) * Ny;
            erow[lane] = e0;
            if (Ny == 128) erow[64 + lane] = e1;
        }
    }

    // phase 5: agg = e @ yv (LDS)
    {
        const int dd = lane & 31, jg = lane >> 5;
        float p = 0.f;
        for (int j = jg; j < Ny; j += 2)
            p = fmaf(sS[(wv << 7) + j], sYV[(j << 5) + dd], p);
        p += __shfl_xor(p, 32);
        if (jg == 0) sAgg[(wv << 5) + dd] = p;
    }
    __syncthreads();

    // phase 7: node-MLP hidden (T overlays u)
    {
        const float4* w14 = (const float4*)(Wn1 + (tid << 6));
        const float b1 = bn1[tid];
        float acc[TI];
        #pragma unroll
        for (int il = 0; il < TI; ++il) acc[il] = b1;
        #pragma unroll
        for (int k = 0; k < 8; ++k) {
            float4 wa = w14[k];
            #pragma unroll
            for (int il = 0; il < TI; ++il)
                acc[il] += dot4(wa, ((const float4*)(sX + (il << 5)))[k]);
        }
        #pragma unroll
        for (int k = 0; k < 8; ++k) {
            float4 wb = w14[8 + k];
            #pragma unroll
            for (int il = 0; il < TI; ++il)
                acc[il] += dot4(wb, ((const float4*)(sAgg + (il << 5)))[k]);
        }
        __syncthreads();
        #pragma unroll
        for (int il = 0; il < TI; ++il) sUT[(il << 8) + tid] = fmaxf(acc[il], 0.f);
    }
    __syncthreads();

    // phase 8: out = x + T @ Wn2^T + bn2
    {
        const int hg = tid >> 5, dd = tid & 31;
        const float4* w24 = (const float4*)(Wn2 + (dd << 8) + (hg << 5));
        float4 w2r[8];
        #pragma unroll
        for (int k = 0; k < 8; ++k) w2r[k] = w24[k];
        float p[TI] = {0.f, 0.f, 0.f, 0.f};
        #pragma unroll
        for (int k = 0; k < 8; ++k) {
            #pragma unroll
            for (int il = 0; il < TI; ++il)
                p[il] += dot4(w2r[k], ((const float4*)(sUT + (il << 8) + (hg << 5)))[k]);
        }
        #pragma unroll
        for (int il = 0; il < TI; ++il) sPR[(hg << 7) + (il << 5) + dd] = p[il];
    }
    __syncthreads();
    if (tid < 128) {
        int il = tid >> 5, dd = tid & 31;
        float a = bn2[dd] + sX[tid];
        #pragma unroll
        for (int hg = 0; hg < 8; ++hg) a += sPR[(hg << 7) + tid];
        outp[((size_t)(b * Nx + i0 + il)) * 32 + dd] = a;
    }
}

// ---------------------------------------------------------------------------
// mega kernel: all 5 stages, 4 grid barriers, one launch.
// GRID=512 co-residency: LDS 70784B -> 2 blocks/CU; VGPR ~104 -> 8 waves/CU;
// 2 x 256 CUs = 512. All blocks resident => barrier safe.
// ---------------------------------------------------------------------------
__global__ __launch_bounds__(256) void mega_kernel(
    const float* robot, const float* frontier, const float* rh, const float* fh,
    const float* robot_frontier, const float* robot_past, const float* frontier_past,
    const float* Wq, const float* bq, const float* Wk, const float* bk,
    const float* Wv, const float* bv, const float* Wn1, const float* bn1,
    const float* Wn2, const float* bn2, const float* We1, const float* be1,
    const float* We2,
    float* out_robot, float* out_frontier, float* out_rh, float* out_fh, float* out_edge,
    float* robot1, float* robot2, float* nf,
    float* w5, float* yv5, float* w6, float* yv6, float* w7, float* yv7,
    unsigned* bar)
{
    __shared__ __align__(16) float smem[SMEM_FLOATS];

    // stage 1: four intra-attentions (416 items)
    for (int it = blockIdx.x; it < 416; it += GRID)
        intra_body(it, smem, robot, frontier, rh, fh,
                   Wq, bq, Wk, bk, Wv, bv, Wn1, bn1, Wn2, bn2,
                   robot1, out_frontier, out_rh, out_fh);
    grid_sync(bar + 0);

    // stage 2: pre_y for inter5 (y=rh1) and inter6 (y=fh1) — 512 items
    for (int it = blockIdx.x; it < 512; it += GRID)
        pre_y_body(it, smem, out_rh, NHh, w5, yv5, BATCH * NHh / 8,
                   out_fh, NFHh, w6, yv6, Wk, bk, Wv, bv, We1);
    grid_sync(bar + 1);

    // stage 3: inter5 (robot1 x rh1) + inter6 (frontier1 x fh1) — 1280 items
    for (int it = blockIdx.x; it < 1280; it += GRID)
        inter_body(it, smem,
                   robot1, NRr, w5, yv5, NHh, robot_past, robot2, (float*)0, BATCH * (NRr / TI),
                   out_frontier, NFf, w6, yv6, NFHh, frontier_past, nf, (float*)0,
                   Wq, bq, We1, be1, We2, Wn1, bn1, Wn2, bn2);
    grid_sync(bar + 2);

    // stage 4: pre_y for inter7 (y = new_frontier) — 512 items
    for (int it = blockIdx.x; it < 512; it += GRID)
        pre_y_body(it, smem, nf, NFf, w7, yv7, BATCH * NFf / 8,
                   nf, NFf, w7, yv7, Wk, bk, Wv, bv, We1);
    grid_sync(bar + 3);

    // stage 5: inter7 (robot2 x new_frontier) -> final robot + edge — 256 items
    for (int it = blockIdx.x; it < 256; it += GRID)
        inter_body(it, smem,
                   robot2, NRr, w7, yv7, NFf, robot_frontier, out_robot, out_edge, BATCH * (NRr / TI),
                   robot2, NRr, w7, yv7, NFf, robot_frontier, out_robot, out_edge,
                   Wq, bq, We1, be1, We2, Wn1, bn1, Wn2, bn2);
}

// ---------------------------------------------------------------------------
extern "C" void kernel_launch(void* const* d_in, const int* in_sizes, int n_in,
                              void* d_out, int out_size, void* d_ws, size_t ws_size,
                              hipStream_t stream) {
    const float* robot          = (const float*)d_in[0];
    const float* frontier       = (const float*)d_in[1];
    const float* rh             = (const float*)d_in[2];
    const float* fh             = (const float*)d_in[3];
    const float* robot_frontier = (const float*)d_in[4];
    const float* robot_past     = (const float*)d_in[5];
    const float* frontier_past  = (const float*)d_in[6];
    const float* Wq  = (const float*)d_in[7];  const float* bq  = (const float*)d_in[8];
    const float* Wk  = (const float*)d_in[9];  const float* bk  = (const float*)d_in[10];
    const float* Wv  = (const float*)d_in[11]; const float* bv  = (const float*)d_in[12];
    const float* Wn1 = (const float*)d_in[13]; const float* bn1 = (const float*)d_in[14];
    const float* Wn2 = (const float*)d_in[15]; const float* bn2 = (const float*)d_in[16];
    const float* We1 = (const float*)d_in[17]; const float* be1 = (const float*)d_in[18];
    const float* We2 = (const float*)d_in[19];

    float* out = (float*)d_out;
    float* out_robot    = out;            // 32*32*32   = 32768
    float* out_frontier = out + 32768;    // 32*128*32  = 131072
    float* out_rh       = out + 163840;   // 32*64*32   = 65536
    float* out_fh       = out + 229376;   // 32*64*32   = 65536
    float* out_edge     = out + 294912;   // 32*32*128  = 131072

    float* W = (float*)d_ws;
    float* robot1 = W;                 // 32768
    float* robot2 = W + 32768;         // 32768
    float* nf     = W + 65536;         // 131072
    float* w5     = W + 196608;        // 524288 (wT layout)
    float* yv5    = W + 720896;        // 65536
    float* w6     = W + 786432;        // 524288 (wT layout)
    float* yv6    = W + 1310720;       // 65536
    float* w7     = W + 1376256;       // 1048576 (wT layout)
    float* yv7    = W + 2424832;       // 131072 -> ends 2555904
    unsigned* bar = (unsigned*)(W + 2555904);  // 4 barrier counters

    hipMemsetAsync(bar, 0, 64, stream);
    mega_kernel<<<GRID, 256, 0, stream>>>(
        robot, frontier, rh, fh, robot_frontier, robot_past, frontier_past,
        Wq, bq, Wk, bk, Wv, bv, Wn1, bn1, Wn2, bn2, We1, be1, We2,
        out_robot, out_frontier, out_rh, out_fh, out_edge,
        robot1, robot2, nf, w5, yv5, w6, yv6, w7, yv7, bar);
}

// Round 9
// 234.546 us; speedup vs baseline: 2.9730x; 1.6819x over previous
//
#include <hip/hip_runtime.h>

#define BATCH 32
#define NRr 32
#define NFf 128
#define NHh 64
#define NFHh 64
#define TI 4

__device__ __forceinline__ float dot4(float4 a, float4 b) {
    return fmaf(a.x, b.x, fmaf(a.y, b.y, fmaf(a.z, b.z, a.w * b.w)));
}

// ---------------------------------------------------------------------------
// intra: x -> x + nmlp([x, softmax(qk^T) v]) for all 4 tensors, 416 blocks:
// [0,32) robot (CH=32), [32,288) frontier (CH=16), [288,352) rh, [352,416) fh.
// rh/fh blocks also emit the y-side precompute (w5/yv5, w6/yv6) for their own
// 32 rows in a LIGHT tail: no hoisted weight arrays (R3's spill cause).
// Score rows padded to pitch N+4 (softmax bank-conflict fix).
// ---------------------------------------------------------------------------
__global__ __launch_bounds__(256) void intra_kernel(
    const float* __restrict__ robot, const float* __restrict__ frontier,
    const float* __restrict__ rhist, const float* __restrict__ fhist,
    const float* __restrict__ Wq, const float* __restrict__ bq,
    const float* __restrict__ Wk, const float* __restrict__ bk,
    const float* __restrict__ Wv, const float* __restrict__ bv,
    const float* __restrict__ Wn1, const float* __restrict__ bn1,
    const float* __restrict__ Wn2, const float* __restrict__ bn2,
    const float* __restrict__ We1,
    float* __restrict__ o_robot, float* __restrict__ o_frontier,
    float* __restrict__ o_rh, float* __restrict__ o_fh,
    float* __restrict__ w5, float* __restrict__ yv5,
    float* __restrict__ w6, float* __restrict__ yv6)
{
    __shared__ __align__(16) float sXc[1024];   // chunk rows of x
    __shared__ __align__(16) float sQ[1024];    // q; later out rows (tail)
    __shared__ __align__(16) float sAgg[1024];
    __shared__ __align__(16) float sS[2304];    // scores, pitch N+4
    __shared__ __align__(16) float sKT[4128];   // K^T [32][129]; tail: yk [32][33]
    __shared__ __align__(16) float sVT[8192];   // V [N][32], then T [CH][256]

    const int item = blockIdx.x, tid = threadIdx.x;
    const float* xin; float* xout; int N, lgN, b, chunk, CH;
    float* wOut = nullptr; float* yvOut = nullptr;
    if (item < 32)       { xin=robot;    xout=o_robot;    N=32;  lgN=5; b=item;  chunk=0;  CH=32; }
    else if (item < 288) { int t=item-32;  xin=frontier; xout=o_frontier; N=128; lgN=7; b=t>>3; chunk=t&7; CH=16; }
    else if (item < 352) { int t=item-288; xin=rhist;    xout=o_rh;       N=64;  lgN=6; b=t>>1; chunk=t&1; CH=32; wOut=w5; yvOut=yv5; }
    else                 { int t=item-352; xin=fhist;    xout=o_fh;       N=64;  lgN=6; b=t>>1; chunk=t&1; CH=32; wOut=w6; yvOut=yv6; }
    const bool isPre = (wOut != nullptr);
    const int P = N + 4;
    const float* xb = xin + (size_t)b * N * 32;
    const int r0 = chunk * CH;
    const int d = tid & 31;

    // load CH rows of x into LDS
    for (int idx = tid; idx < (CH << 5); idx += 256)
        sXc[idx] = xb[(r0 << 5) + idx];

    // K^T, V for all N rows; weight rows hoisted (main body — this is fine)
    {
        const float4* wk4 = (const float4*)(Wk + (d << 5));
        const float4* wv4 = (const float4*)(Wv + (d << 5));
        float4 wk[8], wv[8];
        #pragma unroll
        for (int k = 0; k < 8; ++k) { wk[k] = wk4[k]; wv[k] = wv4[k]; }
        const float bkd = bk[d], bvd = bv[d];
        for (int idx = tid; idx < (N << 5); idx += 256) {
            int j = idx >> 5;
            const float4* xr = (const float4*)(xb + (j << 5));
            float aK = bkd, aV = bvd;
            #pragma unroll
            for (int k = 0; k < 8; ++k) {
                float4 xv = xr[k];
                aK += dot4(wk[k], xv);
                aV += dot4(wv[k], xv);
            }
            sKT[d * 129 + j] = aK;
            sVT[(j << 5) + d] = aV;
        }
    }
    __syncthreads();

    // Q for CH rows
    {
        const float4* wq4 = (const float4*)(Wq + (d << 5));
        float4 wq[8];
        #pragma unroll
        for (int k = 0; k < 8; ++k) wq[k] = wq4[k];
        const float bqd = bq[d];
        for (int idx = tid; idx < (CH << 5); idx += 256) {
            int r = idx >> 5;
            const float4* xr = (const float4*)(sXc + (r << 5));
            float a = bqd;
            #pragma unroll
            for (int k = 0; k < 8; ++k) a += dot4(wq[k], xr[k]);
            sQ[idx] = a;
        }
    }
    __syncthreads();

    // scores: CH x N, pitch P
    for (int idx = tid; idx < CH * N; idx += 256) {
        int r = idx >> lgN, j = idx & (N - 1);
        const float* qr = sQ + (r << 5);
        float a = 0.f;
        #pragma unroll
        for (int e = 0; e < 32; ++e) a = fmaf(qr[e], sKT[e * 129 + j], a);
        sS[r * P + j] = a;
    }
    __syncthreads();

    // softmax per row: lpr = 256/CH lanes per row
    {
        const int lpr = 256 / CH;
        int r = tid / lpr, l = tid % lpr;
        float* row = sS + r * P;
        float m = -1e30f;
        for (int j = l; j < N; j += lpr) m = fmaxf(m, row[j]);
        for (int msk = lpr >> 1; msk; msk >>= 1) m = fmaxf(m, __shfl_xor(m, msk));
        float s = 0.f;
        for (int j = l; j < N; j += lpr) { float ev = __expf(row[j] - m); row[j] = ev; s += ev; }
        for (int msk = lpr >> 1; msk; msk >>= 1) s += __shfl_xor(s, msk);
        float inv = 1.0f / s;
        for (int j = l; j < N; j += lpr) row[j] *= inv;
    }
    __syncthreads();

    // agg = e @ V
    for (int idx = tid; idx < (CH << 5); idx += 256) {
        int r = idx >> 5;
        const float* er = sS + r * P;
        float a = 0.f;
        for (int j = 0; j < N; ++j) a = fmaf(er[j], sVT[(j << 5) + d], a);
        sAgg[idx] = a;
    }
    __syncthreads();

    // T = relu([x, agg] @ Wn1^T + bn1)
    float* sT = sVT;
    {
        const float4* w14 = (const float4*)(Wn1 + (tid << 6));
        float4 w1r[16];
        #pragma unroll
        for (int k = 0; k < 16; ++k) w1r[k] = w14[k];
        const float b1 = bn1[tid];
        for (int r = 0; r < CH; ++r) {
            const float4* xr = (const float4*)(sXc + (r << 5));
            const float4* ar = (const float4*)(sAgg + (r << 5));
            float a = b1;
            #pragma unroll
            for (int k = 0; k < 8; ++k) a += dot4(w1r[k], xr[k]);
            #pragma unroll
            for (int k = 0; k < 8; ++k) a += dot4(w1r[8 + k], ar[k]);
            sT[(r << 8) + tid] = fmaxf(a, 0.f);
        }
    }
    __syncthreads();

    // out = x + T @ Wn2^T + bn2; (rg, d), CH/8 rows each
    {
        const int rg = tid >> 5;
        const int PR = CH >> 3;
        float acc[4] = {0.f, 0.f, 0.f, 0.f};
        #pragma unroll
        for (int hc = 0; hc < 4; ++hc) {
            const float4* w24 = (const float4*)(Wn2 + (d << 8) + (hc << 6));
            float4 w2r[16];
            #pragma unroll
            for (int k = 0; k < 16; ++k) w2r[k] = w24[k];
            for (int p = 0; p < PR; ++p) {
                int r = rg + (p << 3);
                const float4* tr = (const float4*)(sT + (r << 8) + (hc << 6));
                float a = 0.f;
                #pragma unroll
                for (int k = 0; k < 16; ++k) a += dot4(w2r[k], tr[k]);
                acc[p] += a;
            }
        }
        const float b2 = bn2[d];
        for (int p = 0; p < PR; ++p) {
            int r = rg + (p << 3);
            float v = sXc[(r << 5) + d] + b2 + acc[p];
            xout[((size_t)b * N << 5) + ((r0 + r) << 5) + d] = v;
            if (isPre) sQ[(r << 5) + d] = v;   // keep out rows for tail
        }
    }

    // ---- light fused pre_y tail (rh/fh only; N=64, CH=32) ----
    if (isPre) {
        __syncthreads();
        {   // yk -> sKT[r*33+d], yv -> global; NO weight hoist across p
            const float4* wk4 = (const float4*)(Wk + (d << 5));
            const float4* wv4 = (const float4*)(Wv + (d << 5));
            const float bkd = bk[d], bvd = bv[d];
            const int rg = tid >> 5;
            for (int p = 0; p < 4; ++p) {
                int r = rg + (p << 3);
                const float4* orow = (const float4*)(sQ + (r << 5));
                float aK = bkd, aV = bvd;
                #pragma unroll
                for (int k = 0; k < 8; ++k) {
                    float4 ov = orow[k];
                    aK += dot4(wk4[k], ov);
                    aV += dot4(wv4[k], ov);
                }
                sKT[r * 33 + d] = aK;
                yvOut[(((size_t)(b * N + r0 + r)) << 5) + d] = aV;
            }
        }
        __syncthreads();
        {   // w rows: thread h = tid, 32 j's in 4 chunks of 8; wT packed store
            const float* w1 = We1 + tid * 65 + 32;
            for (int rc = 0; rc < 4; ++rc) {
                float acc[8] = {0,0,0,0,0,0,0,0};
                #pragma unroll
                for (int e = 0; e < 32; ++e) {
                    float we = w1[e];
                    #pragma unroll
                    for (int jl = 0; jl < 8; ++jl)
                        acc[jl] = fmaf(we, sKT[(rc * 8 + jl) * 33 + e], acc[jl]);
                }
                float* wbase = wOut + (((size_t)b * 64 + (tid >> 2)) * 64 + r0 + (rc << 3)) * 4 + (tid & 3);
                #pragma unroll
                for (int jl = 0; jl < 8; ++jl)
                    wbase[jl << 2] = acc[jl];
            }
        }
    }
}

// ---------------------------------------------------------------------------
// inter v5: block = (b, 4 i's). Phase 3 splits h across the 4 waves (partials
// exact: score linear after ReLU). wT layout: ((b*64+h/4)*Ny + j)*4 + h%4.
// Stage-B blocks optionally emit w/yv precompute for the NEXT stage from their
// own 4 out rows (light tail, no weight hoisting).
// ---------------------------------------------------------------------------
__global__ __launch_bounds__(256) void inter_main_kernel(
    const float* __restrict__ xA, int NxA, const float* __restrict__ wA, const float* __restrict__ yvA,
    int NyA, const float* __restrict__ disA, float* __restrict__ outA, float* __restrict__ eA,
    float* __restrict__ wPreA, float* __restrict__ yvPreA, int nBlkA,
    const float* __restrict__ xB, int NxB, const float* __restrict__ wB, const float* __restrict__ yvB,
    int NyB, const float* __restrict__ disB, float* __restrict__ outB, float* __restrict__ eB,
    float* __restrict__ wPreB, float* __restrict__ yvPreB,
    const float* __restrict__ Wq, const float* __restrict__ bq,
    const float* __restrict__ Wk, const float* __restrict__ bk,
    const float* __restrict__ Wv, const float* __restrict__ bv,
    const float* __restrict__ We1, const float* __restrict__ be1,
    const float* __restrict__ We2,
    const float* __restrict__ Wn1, const float* __restrict__ bn1,
    const float* __restrict__ Wn2, const float* __restrict__ bn2)
{
    __shared__ __align__(16) float sX[128];
    __shared__ __align__(16) float sQ[128];      // q; later out rows (tail)
    __shared__ __align__(16) float sAgg[128];
    __shared__ __align__(16) float sDis[512];    // [4][128]
    __shared__ __align__(16) float sC[256];
    __shared__ __align__(16) float sW2[256];
    __shared__ __align__(16) float sS[512];      // scores/e; tail: yk [4][33]
    __shared__ __align__(16) float sUT[1024];    // u (ph2-3), then T (ph7-8)
    __shared__ __align__(16) float sPR[2048];    // partials (ph3), red (ph8)
    __shared__ __align__(16) float sYV[4096];    // yv tile [Ny][32]

    const int blk = blockIdx.x, tid = threadIdx.x;
    const float* x; int Nx; const float* w; const float* yv; int Ny;
    const float* dis; float* outp; float* ep; float* wPre; float* yvPre; int idx;
    if (blk < nBlkA) { x=xA; Nx=NxA; w=wA; yv=yvA; Ny=NyA; dis=disA; outp=outA; ep=eA; wPre=wPreA; yvPre=yvPreA; idx=blk; }
    else             { x=xB; Nx=NxB; w=wB; yv=yvB; Ny=NyB; dis=disB; outp=outB; ep=eB; wPre=wPreB; yvPre=yvPreB; idx=blk-nBlkA; }
    const int lgNy = (Ny == 128) ? 7 : 6;
    const int tiles = Nx >> 2;
    const int b = idx / tiles, i0 = (idx - b * tiles) << 2;
    const float* xrow = x + ((size_t)(b * Nx + i0)) * 32;

    // phase 0: stage x, dis, yv
    if (tid < 128) sX[tid] = xrow[tid];
    if (tid < Ny) {
        int il = tid >> (lgNy - 2), jq = tid & ((Ny >> 2) - 1);
        ((float4*)sDis)[(il << 5) + jq] =
            ((const float4*)(dis + ((size_t)(b * Nx + i0 + il)) * Ny))[jq];
    }
    {
        const float4* yv4 = (const float4*)(yv + ((size_t)(b * Ny) << 5));
        for (int k = tid; k < (Ny << 3); k += 256)
            ((float4*)sYV)[k] = yv4[k];
    }
    __syncthreads();

    // phase 1: Q
    if (tid < 128) {
        int il = tid >> 5, dd = tid & 31;
        const float4* wq4 = (const float4*)(Wq + (dd << 5));
        const float4* xr = (const float4*)(sX + (il << 5));
        float a = bq[dd];
        #pragma unroll
        for (int k = 0; k < 8; ++k) a += dot4(wq4[k], xr[k]);
        sQ[tid] = a;
    }
    __syncthreads();

    // phase 2: u, c, w2
    {
        const float* w1 = We1 + tid * 65;
        const float b1 = be1[tid];
        float acc[TI];
        #pragma unroll
        for (int il = 0; il < TI; ++il) acc[il] = b1;
        #pragma unroll
        for (int e = 0; e < 32; ++e) {
            float we = w1[e];
            #pragma unroll
            for (int il = 0; il < TI; ++il)
                acc[il] = fmaf(we, sQ[(il << 5) + e], acc[il]);
        }
        #pragma unroll
        for (int il = 0; il < TI; ++il) sUT[(il << 8) + tid] = acc[il];
        sC[tid] = w1[64];
        sW2[tid] = We2[tid];
    }
    __syncthreads();

    // phase 3: scores; wave wv owns h-quarter, lane = j, all 4 i's
    const int wv = tid >> 6, lane = tid & 63;
    {
        const int hc0 = wv << 4;
        const float4* wT4 = (const float4*)w + (size_t)(b * 64) * Ny;
        const float4* c4p = (const float4*)sC;
        const float4* p4p = (const float4*)sW2;
        if (Ny == 64) {
            float dv[TI];
            #pragma unroll
            for (int il = 0; il < TI; ++il) dv[il] = sDis[(il << 7) + lane];
            float acc[TI] = {0.f, 0.f, 0.f, 0.f};
            #pragma unroll
            for (int t = 0; t < 16; ++t) {
                int hc = hc0 + t;
                float4 w4 = wT4[((size_t)hc << 6) + lane];
                float4 c4 = c4p[hc], p4 = p4p[hc];
                #pragma unroll
                for (int il = 0; il < TI; ++il) {
                    float4 u4 = ((const float4*)(sUT + (il << 8)))[hc];
                    acc[il] = fmaf(p4.x, fmaxf(fmaf(c4.x, dv[il], u4.x + w4.x), 0.f), acc[il]);
                    acc[il] = fmaf(p4.y, fmaxf(fmaf(c4.y, dv[il], u4.y + w4.y), 0.f), acc[il]);
                    acc[il] = fmaf(p4.z, fmaxf(fmaf(c4.z, dv[il], u4.z + w4.z), 0.f), acc[il]);
                    acc[il] = fmaf(p4.w, fmaxf(fmaf(c4.w, dv[il], u4.w + w4.w), 0.f), acc[il]);
                }
            }
            #pragma unroll
            for (int il = 0; il < TI; ++il)
                sPR[(wv << 9) + (il << 7) + lane] = acc[il];
        } else {
            float dv0[TI], dv1[TI];
            #pragma unroll
            for (int il = 0; il < TI; ++il) {
                dv0[il] = sDis[(il << 7) + lane];
                dv1[il] = sDis[(il << 7) + 64 + lane];
            }
            float acc0[TI] = {0.f, 0.f, 0.f, 0.f};
            float acc1[TI] = {0.f, 0.f, 0.f, 0.f};
            #pragma unroll
            for (int t = 0; t < 16; ++t) {
                int hc = hc0 + t;
                float4 wa = wT4[((size_t)hc << 7) + lane];
                float4 wb = wT4[((size_t)hc << 7) + 64 + lane];
                float4 c4 = c4p[hc], p4 = p4p[hc];
                #pragma unroll
                for (int il = 0; il < TI; ++il) {
                    float4 u4 = ((const float4*)(sUT + (il << 8)))[hc];
                    acc0[il] = fmaf(p4.x, fmaxf(fmaf(c4.x, dv0[il], u4.x + wa.x), 0.f), acc0[il]);
                    acc0[il] = fmaf(p4.y, fmaxf(fmaf(c4.y, dv0[il], u4.y + wa.y), 0.f), acc0[il]);
                    acc0[il] = fmaf(p4.z, fmaxf(fmaf(c4.z, dv0[il], u4.z + wa.z), 0.f), acc0[il]);
                    acc0[il] = fmaf(p4.w, fmaxf(fmaf(c4.w, dv0[il], u4.w + wa.w), 0.f), acc0[il]);
                    acc1[il] = fmaf(p4.x, fmaxf(fmaf(c4.x, dv1[il], u4.x + wb.x), 0.f), acc1[il]);
                    acc1[il] = fmaf(p4.y, fmaxf(fmaf(c4.y, dv1[il], u4.y + wb.y), 0.f), acc1[il]);
                    acc1[il] = fmaf(p4.z, fmaxf(fmaf(c4.z, dv1[il], u4.z + wb.z), 0.f), acc1[il]);
                    acc1[il] = fmaf(p4.w, fmaxf(fmaf(c4.w, dv1[il], u4.w + wb.w), 0.f), acc1[il]);
                }
            }
            #pragma unroll
            for (int il = 0; il < TI; ++il) {
                sPR[(wv << 9) + (il << 7) + lane] = acc0[il];
                sPR[(wv << 9) + (il << 7) + 64 + lane] = acc1[il];
            }
        }
    }
    __syncthreads();

    // reduce h-quarter partials into sS
    for (int k = tid; k < (TI << lgNy); k += 256) {
        int il = k >> lgNy, j = k & (Ny - 1);
        int o = (il << 7) + j;
        sS[o] = sPR[o] + sPR[512 + o] + sPR[1024 + o] + sPR[1536 + o];
    }
    __syncthreads();

    // phase 4: softmax per wave + edge write
    {
        float v0 = sS[(wv << 7) + lane];
        float v1 = (Ny == 128) ? sS[(wv << 7) + 64 + lane] : -1e30f;
        float m = fmaxf(v0, v1);
        #pragma unroll
        for (int msk = 32; msk; msk >>= 1) m = fmaxf(m, __shfl_xor(m, msk));
        float e0 = __expf(v0 - m);
        float e1 = (Ny == 128) ? __expf(v1 - m) : 0.f;
        float s = e0 + e1;
        #pragma unroll
        for (int msk = 32; msk; msk >>= 1) s += __shfl_xor(s, msk);
        float inv = 1.0f / s;
        e0 *= inv; e1 *= inv;
        sS[(wv << 7) + lane] = e0;
        if (Ny == 128) sS[(wv << 7) + 64 + lane] = e1;
        if (ep) {
            float* erow = ep + ((size_t)(b * Nx + i0 + wv)) * Ny;
            erow[lane] = e0;
            if (Ny == 128) erow[64 + lane] = e1;
        }
    }

    // phase 5: agg = e @ yv (LDS)
    {
        const int dd = lane & 31, jg = lane >> 5;
        float p = 0.f;
        for (int j = jg; j < Ny; j += 2)
            p = fmaf(sS[(wv << 7) + j], sYV[(j << 5) + dd], p);
        p += __shfl_xor(p, 32);
        if (jg == 0) sAgg[(wv << 5) + dd] = p;
    }
    __syncthreads();

    // phase 7: node-MLP hidden (T overlays u)
    {
        const float4* w14 = (const float4*)(Wn1 + (tid << 6));
        const float b1 = bn1[tid];
        float acc[TI];
        #pragma unroll
        for (int il = 0; il < TI; ++il) acc[il] = b1;
        #pragma unroll
        for (int k = 0; k < 8; ++k) {
            float4 wa = w14[k];
            #pragma unroll
            for (int il = 0; il < TI; ++il)
                acc[il] += dot4(wa, ((const float4*)(sX + (il << 5)))[k]);
        }
        #pragma unroll
        for (int k = 0; k < 8; ++k) {
            float4 wb = w14[8 + k];
            #pragma unroll
            for (int il = 0; il < TI; ++il)
                acc[il] += dot4(wb, ((const float4*)(sAgg + (il << 5)))[k]);
        }
        __syncthreads();
        #pragma unroll
        for (int il = 0; il < TI; ++il) sUT[(il << 8) + tid] = fmaxf(acc[il], 0.f);
    }
    __syncthreads();

    // phase 8: out = x + T @ Wn2^T + bn2
    {
        const int hg = tid >> 5, dd = tid & 31;
        const float4* w24 = (const float4*)(Wn2 + (dd << 8) + (hg << 5));
        float4 w2r[8];
        #pragma unroll
        for (int k = 0; k < 8; ++k) w2r[k] = w24[k];
        float p[TI] = {0.f, 0.f, 0.f, 0.f};
        #pragma unroll
        for (int k = 0; k < 8; ++k) {
            #pragma unroll
            for (int il = 0; il < TI; ++il)
                p[il] += dot4(w2r[k], ((const float4*)(sUT + (il << 8) + (hg << 5)))[k]);
        }
        #pragma unroll
        for (int il = 0; il < TI; ++il) sPR[(hg << 7) + (il << 5) + dd] = p[il];
    }
    __syncthreads();
    if (tid < 128) {
        int il = tid >> 5, dd = tid & 31;
        float a = bn2[dd] + sX[tid];
        #pragma unroll
        for (int hg = 0; hg < 8; ++hg) a += sPR[(hg << 7) + tid];
        outp[((size_t)(b * Nx + i0 + il)) * 32 + dd] = a;
        if (wPre) sQ[tid] = a;     // keep out rows for tail (sQ dead since ph2)
    }

    // ---- light fused pre tail (stage-6 blocks): w/yv for the next stage ----
    if (wPre) {
        __syncthreads();
        {   // yk -> sS[il*33+dd] (sS dead), yv -> global
            int t = tid & 127, il = t >> 5, dd = t & 31;
            const float4* wm4 = (const float4*)(((tid < 128) ? Wk : Wv) + (dd << 5));
            const float4* orow = (const float4*)(sQ + (il << 5));
            float a = (tid < 128) ? bk[dd] : bv[dd];
            #pragma unroll
            for (int k = 0; k < 8; ++k) a += dot4(wm4[k], orow[k]);
            if (tid < 128) sS[il * 33 + dd] = a;
            else yvPre[(((size_t)(b * Nx + i0 + il)) << 5) + dd] = a;
        }
        __syncthreads();
        {   // w rows for 4 j's; wT packed store (next-stage Ny == Nx here)
            const float* w1 = We1 + tid * 65 + 32;
            float acc[4] = {0.f, 0.f, 0.f, 0.f};
            #pragma unroll
            for (int e = 0; e < 32; ++e) {
                float we = w1[e];
                #pragma unroll
                for (int il = 0; il < 4; ++il)
                    acc[il] = fmaf(we, sS[il * 33 + e], acc[il]);
            }
            float* wbase = wPre + (((size_t)b * 64 + (tid >> 2)) * Nx + i0) * 4 + (tid & 3);
            #pragma unroll
            for (int il = 0; il < 4; ++il)
                wbase[il << 2] = acc[il];
        }
    }
}

// ---------------------------------------------------------------------------
extern "C" void kernel_launch(void* const* d_in, const int* in_sizes, int n_in,
                              void* d_out, int out_size, void* d_ws, size_t ws_size,
                              hipStream_t stream) {
    const float* robot          = (const float*)d_in[0];
    const float* frontier       = (const float*)d_in[1];
    const float* rh             = (const float*)d_in[2];
    const float* fh             = (const float*)d_in[3];
    const float* robot_frontier = (const float*)d_in[4];
    const float* robot_past     = (const float*)d_in[5];
    const float* frontier_past  = (const float*)d_in[6];
    const float* Wq  = (const float*)d_in[7];  const float* bq  = (const float*)d_in[8];
    const float* Wk  = (const float*)d_in[9];  const float* bk  = (const float*)d_in[10];
    const float* Wv  = (const float*)d_in[11]; const float* bv  = (const float*)d_in[12];
    const float* Wn1 = (const float*)d_in[13]; const float* bn1 = (const float*)d_in[14];
    const float* Wn2 = (const float*)d_in[15]; const float* bn2 = (const float*)d_in[16];
    const float* We1 = (const float*)d_in[17]; const float* be1 = (const float*)d_in[18];
    const float* We2 = (const float*)d_in[19];

    float* out = (float*)d_out;
    float* out_robot    = out;            // 32*32*32   = 32768
    float* out_frontier = out + 32768;    // 32*128*32  = 131072
    float* out_rh       = out + 163840;   // 32*64*32   = 65536
    float* out_fh       = out + 229376;   // 32*64*32   = 65536
    float* out_edge     = out + 294912;   // 32*32*128  = 131072

    float* W = (float*)d_ws;
    float* robot1 = W;                 // 32768
    float* robot2 = W + 32768;         // 32768
    float* nf     = W + 65536;         // 131072
    float* w5     = W + 196608;        // 524288 (wT layout)
    float* yv5    = W + 720896;        // 65536
    float* w6     = W + 786432;        // 524288 (wT layout)
    float* yv6    = W + 1310720;       // 65536
    float* w7     = W + 1376256;       // 1048576 (wT layout)
    float* yv7    = W + 2424832;       // 131072

    // A: four intra-attentions + fused pre_y for stages 5/6 (rh/fh blocks)
    intra_kernel<<<416, 256, 0, stream>>>(robot, frontier, rh, fh,
        Wq, bq, Wk, bk, Wv, bv, Wn1, bn1, Wn2, bn2, We1,
        robot1, out_frontier, out_rh, out_fh, w5, yv5, w6, yv6);

    // B: inter5 (robot1 x rh1) + inter6 (frontier1 x fh1, fused pre_y7 tail)
    inter_main_kernel<<<1280, 256, 0, stream>>>(
        robot1, NRr, w5, yv5, NHh, robot_past, robot2,
        (float*)nullptr, (float*)nullptr, (float*)nullptr, BATCH * (NRr / TI),
        out_frontier, NFf, w6, yv6, NFHh, frontier_past, nf,
        (float*)nullptr, w7, yv7,
        Wq, bq, Wk, bk, Wv, bv, We1, be1, We2, Wn1, bn1, Wn2, bn2);

    // C: inter7 (robot2 x new_frontier) -> final robot + edge
    inter_main_kernel<<<256, 256, 0, stream>>>(
        robot2, NRr, w7, yv7, NFf, robot_frontier, out_robot, out_edge,
        (float*)nullptr, (float*)nullptr, BATCH * (NRr / TI),
        robot2, NRr, w7, yv7, NFf, robot_frontier, out_robot, out_edge,
        (float*)nullptr, (float*)nullptr,
        Wq, bq, Wk, bk, Wv, bv, We1, be1, We2, Wn1, bn1, Wn2, bn2);
}